// Round 12
// baseline (1593.346 us; speedup 1.0000x reference)
//
#include <hip/hip_runtime.h>
#include <hip/hip_bf16.h>
#include <cstdint>

typedef _Float16 h8 __attribute__((ext_vector_type(8)));
typedef _Float16 h4 __attribute__((ext_vector_type(4)));
typedef float    f4 __attribute__((ext_vector_type(4)));
typedef float    fx16 __attribute__((ext_vector_type(16)));

// Dims: B=16, Cin=256, Ch=128, Br=8, H=W=64, 4096 px/image, 65536 px total.
// ws layout (25 MB):
//   hr   @ 0          16,777,216 B  (f16 [65536 px][128 ch])
//   W1r  @ 16777216    4,718,592 B  (f16 [ci8][tap9][ch2][gq2][g4][64c][32ch slotXOR])
//   W2r  @ 21495808      524,288 B  (f16 [g][kc4][256co][32ch])
//   sel1 @ 22020096    2,097,152 B  (f32 [b][g][4096])
//   sel2 @ 24117248    2,097,152 B  (f32 [b][g][4096])
//
// LDS involution: 16B slot s at row r lives at slot s ^ ((r>>1)&3)
// (bank-quad of b128 = (r&1)*4 + slot -> 8 consecutive rows cover all 8 quads).
//
// conv1 (R12): R6 math/protocol, OUTPUT-CHANNEL-SPLIT for 2 blocks/CU overlap:
// grid (16 yt, 16 b, 2 ch-half), 512 thr / 8 waves (wm2 x wn4), wave =
// 32ch x 64px (m=1, nf=2, acc=32). Total A-read/staging traffic == R6 (each
// half stages only its 32KB/tap); independent co-resident blocks overlap
// port vs MFMA (m114). wt dbuf = 2 x 16KB (4-expert x 64c chunks, 2 phases/
// tap, buffer index = gq, compile-time); LDS 56.6KB -> 2 blocks/CU at
// __launch_bounds__(512,4).

#define GLD16(src, dst) __builtin_amdgcn_global_load_lds( \
    (const __attribute__((address_space(1))) void*)(src), \
    (__attribute__((address_space(3))) void*)(dst), 16, 0, 0)

// ---------------- prep_w: fp32 -> f16 repack ----------------
__global__ __launch_bounds__(256) void prep_w_k(const float* __restrict__ W1,
        const float* __restrict__ W2, _Float16* __restrict__ W1r,
        _Float16* __restrict__ W2r) {
    int i = blockIdx.x * 256 + threadIdx.x;
    if (i < 2359296) {
        // W1 [g][c][ci][tap] -> W1r [ci>>5][tap][c>>6][g>>2][g&3][c&63][slotXOR(ci&31)]
        int g = i / 294912;  int r  = i - g * 294912;
        int c = r / 2304;    int r2 = r - c * 2304;
        int ci = r2 / 9;     int tap = r2 - ci * 9;
        int s = (ci & 31) >> 3;            // 16B slot 0..3
        int pos = (s ^ ((c >> 1) & 3)) * 8 + (ci & 7);
        W1r[((size_t)((ci >> 5) * 9 + tap)) * 32768
            + (size_t)((c >> 6) * 2 + (g >> 2)) * 8192
            + (g & 3) * 2048 + (c & 63) * 32 + pos] = (_Float16)W1[i];
    } else {
        int i2 = i - 2359296;
        int g = i2 >> 15; int r = i2 & 32767; int co = r >> 7; int ch = r & 127;
        W2r[(((size_t)g * 4 + (ch >> 5)) * 256 + co) * 32 + (ch & 31)]
            = (_Float16)W2[i2];
    }
}

// ---------------- prep_x: sel1 softmax only ----------------
__global__ __launch_bounds__(256) void prep_x_k(const float* __restrict__ x,
        const float* __restrict__ Wc1, const float* __restrict__ bc1,
        float* __restrict__ sel1) {
    __shared__ float wc[2048];            // Wc1 [8][256]
    int t = threadIdx.x;
    for (int i = t; i < 2048; i += 256) wc[i] = Wc1[i];
    __syncthreads();
    int pix = blockIdx.x * 256 + t;       // b*4096 + p
    int b = pix >> 12, p = pix & 4095;
    const float* xp = x + (size_t)b * 1048576 + p;
    float lg[8] = {0.f,0.f,0.f,0.f,0.f,0.f,0.f,0.f};
    for (int c = 0; c < 256; ++c) {
        float v = fmaxf(xp[(size_t)c * 4096], 0.f);
        #pragma unroll
        for (int g = 0; g < 8; ++g) lg[g] += wc[g * 256 + c] * v;
    }
    float m = -1e30f;
    #pragma unroll
    for (int g = 0; g < 8; ++g) { lg[g] += bc1[g]; m = fmaxf(m, lg[g]); }
    float sum = 0.f;
    #pragma unroll
    for (int g = 0; g < 8; ++g) { lg[g] = __expf(lg[g] - m); sum += lg[g]; }
    float inv = 1.f / sum;
    #pragma unroll
    for (int g = 0; g < 8; ++g)
        sel1[(size_t)(b * 8 + g) * 4096 + p] = lg[g] * inv;
}

// ---------------- conv1: switched 3x3, 64c x 256px per block, 32x32x16 MFMA --
__global__ __launch_bounds__(512, 4) void conv1_k(const float* __restrict__ x,
        const _Float16* __restrict__ W1r, const float* __restrict__ sel1,
        const float* __restrict__ b1, _Float16* __restrict__ hr) {
    __shared__ _Float16 wt[2][8192];      // dbuf 16KB: [g4][64c][32ch slotXOR]
    __shared__ _Float16 xs[12320];        // [6 rows][64 col][32 ch slotXOR] + zero @12288
    int t = threadIdx.x;
    int b = blockIdx.y, yt = blockIdx.x, chb = blockIdx.z;   // chb: 64-ch half
    int y0 = yt * 4;
    int w = t >> 6, l = t & 63;
    int wm = w >> 2, wn = w & 3;          // wm: 32-ch strip of block's 64, wn: 64-px
    int l31 = l & 31, kq2 = l >> 5;
    if (t < 32) xs[12288 + t] = (_Float16)0.f;   // zero slot (covers ^16)

    fx16 acc[2];                          // [nf] -> 32 f32/lane
    #pragma unroll
    for (int n = 0; n < 2; ++n)
        #pragma unroll
        for (int e = 0; e < 16; ++e) acc[n][e] = 0.f;

    auto stage_w = [&](int P, _Float16* dwb) {   // P = tap*2 + gq; 16KB chunk
        const _Float16* srcw = W1r
            + ((size_t)(P >> 1) * 4 + chb * 2 + (P & 1)) * 8192 + t * 8;
        _Float16* dw = dwb + t * 8;
        #pragma unroll
        for (int it = 0; it < 2; ++it)
            GLD16(srcw + it * 4096, dw + it * 4096);
    };

    // lane constants
    int px[2];
    #pragma unroll
    for (int nf = 0; nf < 2; ++nf) px[nf] = wn * 64 + nf * 32 + l31;   // [0,256)
    bool e0 = (l31 == 0), e63 = (l31 == 31);
    int afo[2];                           // A offset within chunk, c local [0,64)
    #pragma unroll
    for (int kc = 0; kc < 2; ++kc) {
        int c = wm * 32 + l31;
        afo[kc] = c * 32 + (((kc * 2 + kq2) ^ ((c >> 1) & 3)) * 8);
    }
    int ba[2][3];                         // kc=0 bases; kc=1 via ^16
    #pragma unroll
    for (int nf = 0; nf < 2; ++nf)
        #pragma unroll
        for (int kx = 0; kx < 3; ++kx) {
            int rz = px[nf] + kx - 1;
            ba[nf][kx] = rz * 32 + ((kq2 ^ ((rz >> 1) & 3)) * 8);
        }
    h8 selv[2];                           // routing weights, element g
    #pragma unroll
    for (int nf = 0; nf < 2; ++nf)
        #pragma unroll
        for (int g = 0; g < 8; ++g)
            selv[nf][g] = (_Float16)sel1[(size_t)(b * 8 + g) * 4096 + yt * 256 + px[nf]];

    stage_w(0, wt[0]);                    // prologue
    #pragma unroll 1
    for (int ci = 0; ci < 8; ++ci) {
        __syncthreads();                  // (A) prev xs readers done
        if (t < 384) {                    // stage relu(x): 6 rows x 64 col x 32 ch
            int r = t >> 6, col = t & 63;
            int rc = r * 64 + col;
            int yi = y0 - 1 + r;
            _Float16* dx = xs + rc * 32;
            int rx = (rc >> 1) & 3;
            if (yi >= 0 && yi < 64) {
                const float* xp = x + ((size_t)(b * 256 + ci * 32)) * 4096 + yi * 64 + col;
                float v[32];
                #pragma unroll
                for (int c2 = 0; c2 < 32; ++c2)
                    v[c2] = fmaxf(xp[(size_t)c2 * 4096], 0.f);
                #pragma unroll
                for (int qq = 0; qq < 4; ++qq) {
                    h8 hv;
                    #pragma unroll
                    for (int e = 0; e < 8; ++e) hv[e] = (_Float16)v[qq * 8 + e];
                    *(h8*)(dx + (qq ^ rx) * 8) = hv;   // involution: read undoes it
                }
            } else {
                const h8 HZ = {};
                #pragma unroll
                for (int qq = 0; qq < 4; ++qq)
                    *(h8*)(dx + (qq ^ rx) * 8) = HZ;
            }
        }
        #pragma unroll 1
        for (int ky = 0; ky < 3; ++ky) {
            #pragma unroll
            for (int kx = 0; kx < 3; ++kx) {
                int tap = ci * 9 + ky * 3 + kx;
                h8 bfr[2][2];             // [nf][kc], loaded at gq==0
                #pragma unroll
                for (int gq = 0; gq < 2; ++gq) {
                    int P = tap * 2 + gq;
                    __syncthreads();      // drains stage of wt[gq]; publishes it (+xs)
                    if (P < 143) stage_w(P + 1, wt[gq ^ 1]);
                    if (gq == 0) {
                        #pragma unroll
                        for (int nf = 0; nf < 2; ++nf) {
                            int a = ba[nf][kx] + ky * 2048;
                            if (kx == 0 && nf == 0) a = e0 ? 12288 : a;
                            if (kx == 2 && nf == 1) a = e63 ? 12288 : a;
                            bfr[nf][0] = *(const h8*)(xs + a);
                            bfr[nf][1] = *(const h8*)(xs + (a ^ 16));
                        }
                    }
                    const _Float16* wp = wt[gq];
                    #pragma unroll
                    for (int g4 = 0; g4 < 4; ++g4) {
                        #pragma unroll
                        for (int kc = 0; kc < 2; ++kc) {
                            h8 a0 = *(const h8*)(wp + g4 * 2048 + afo[kc]);
                            #pragma unroll
                            for (int nf = 0; nf < 2; ++nf) {
                                h8 bs = bfr[nf][kc] * selv[nf][gq * 4 + g4];
                                acc[nf] = __builtin_amdgcn_mfma_f32_32x32x16_f16(
                                    a0, bs, acc[nf], 0, 0, 0);
                            }
                        }
                    }
                }
            }
        }
    }
    // epilogue: + b1, relu, f16, NHWC hr
    // C/D (32x32): col=lane&31, row=(reg&3)+8*(reg>>2)+4*(lane>>5)
    #pragma unroll
    for (int nf = 0; nf < 2; ++nf) {
        size_t pg = ((size_t)(b * 4096 + yt * 256 + px[nf])) * 128;
        #pragma unroll
        for (int q = 0; q < 4; ++q) {
            int c0 = chb * 64 + wm * 32 + q * 8 + kq2 * 4;
            f4 bb = *(const f4*)(b1 + c0);
            h4 hv;
            #pragma unroll
            for (int r = 0; r < 4; ++r)
                hv[r] = (_Float16)fmaxf(acc[nf][q * 4 + r] + bb[r], 0.f);
            *(h4*)(hr + pg + c0) = hv;
        }
    }
}

// ---------------- sel2: coupler-2 softmax from h ----------------
__global__ __launch_bounds__(256) void sel2_k(const _Float16* __restrict__ hr,
        const float* __restrict__ Wc2, const float* __restrict__ bc2,
        float* __restrict__ sel2) {
    __shared__ float wc[1024];   // Wc2 [8][128]
    int t = threadIdx.x;
    for (int i = t; i < 1024; i += 256) wc[i] = Wc2[i];
    __syncthreads();
    int pix = blockIdx.x * 256 + t;
    const h8* hp = (const h8*)(hr + (size_t)pix * 128);
    float lg[8] = {0.f,0.f,0.f,0.f,0.f,0.f,0.f,0.f};
    for (int j = 0; j < 16; ++j) {
        h8 v = hp[j];
        #pragma unroll
        for (int e = 0; e < 8; ++e) {
            float f = (float)v[e];
            int c = j * 8 + e;
            #pragma unroll
            for (int g = 0; g < 8; ++g) lg[g] += wc[g * 128 + c] * f;
        }
    }
    float m = -1e30f;
    #pragma unroll
    for (int g = 0; g < 8; ++g) { lg[g] += bc2[g]; m = fmaxf(m, lg[g]); }
    float sum = 0.f;
    #pragma unroll
    for (int g = 0; g < 8; ++g) { lg[g] = __expf(lg[g] - m); sum += lg[g]; }
    float inv = 1.f / sum;
    int b = pix >> 12, p = pix & 4095;
    #pragma unroll
    for (int g = 0; g < 8; ++g)
        sel2[(size_t)(b * 8 + g) * 4096 + p] = lg[g] * inv;
}

// ---------------- conv2: switched 1x1 + bias + residual, 256co x 64px tile ----
__global__ __launch_bounds__(256, 2) void conv2_k(const _Float16* __restrict__ hr,
        const _Float16* __restrict__ W2r, const float* __restrict__ sel2,
        const float* __restrict__ b2, const float* __restrict__ x,
        float* __restrict__ out) {
    __shared__ _Float16 hs[64 * 128];        // [64 px][128 ch] swizzled
    __shared__ _Float16 wt[2][256 * 32];     // dbuf [256 co][32 ch] swizzled
    int t = threadIdx.x;
    int bid = blockIdx.x;
    int b = bid >> 6, p0 = (bid & 63) * 64;
    int l = t & 63, w = t >> 6;
    int wm = w >> 1, wn = w & 1;
    int l15 = l & 15, sl = l >> 4;
    int swl = (l15 & 7) << 3;
    const f4 FZ = {0.f, 0.f, 0.f, 0.f};
    f4 acce[8][2], accf[8][2];
    #pragma unroll
    for (int m = 0; m < 8; ++m)
        #pragma unroll
        for (int n = 0; n < 2; ++n) { acce[m][n] = FZ; accf[m][n] = FZ; }
    {   // stage h tile (swizzled)
        int px = t >> 2, qq = t & 3;
        const _Float16* src = hr + (size_t)(b * 4096 + p0 + px) * 128 + qq * 32;
        #pragma unroll
        for (int u = 0; u < 4; ++u)
            *(h8*)(hs + ((px * 128 + qq * 32 + u * 8) ^ ((px & 7) << 3)))
                = *(const h8*)(src + u * 8);
    }
    float selr[8][2];
    #pragma unroll
    for (int g = 0; g < 8; ++g)
        #pragma unroll
        for (int n = 0; n < 2; ++n)
            selr[g][n] = sel2[(size_t)(b * 8 + g) * 4096 + p0 + wn * 32 + n * 16 + l15];
    int afo[8];
    #pragma unroll
    for (int m = 0; m < 8; ++m) {
        int c = wm * 128 + m * 16 + l15;
        afo[m] = ((c * 32 + sl * 8) ^ swl);
    }
    h8 wr[4];
    auto load_w = [&](int T) {
        const _Float16* srcw = W2r + (size_t)T * 8192;
        #pragma unroll
        for (int it = 0; it < 4; ++it)
            wr[it] = *(const h8*)(srcw + (size_t)(it * 256 + t) * 8);
    };
    auto write_w = [&](int bf) {
        #pragma unroll
        for (int it = 0; it < 4; ++it) {
            int cc = it * 256 + t;
            int c = cc >> 2, q = cc & 3;
            *(h8*)(wt[bf] + ((c * 32 + q * 8) ^ ((c & 7) << 3))) = wr[it];
        }
    };
    load_w(0);
    write_w(0);
    int buf = 0;
    #pragma unroll 1
    for (int T = 0; T < 32; ++T) {          // T = g*4 + kchunk
        bool hn = (T < 31);
        if (hn) load_w(T + 1);
        __syncthreads();   // publishes wt[buf] (+ hs at T=0)
        int kc = (T & 3) * 32;
        h8 bfv[2];
        #pragma unroll
        for (int n = 0; n < 2; ++n) {
            int px = wn * 32 + n * 16 + l15;
            bfv[n] = *(const h8*)(hs + ((px * 128 + kc + sl * 8) ^ ((px & 7) << 3)));
        }
        #pragma unroll
        for (int m = 0; m < 8; ++m) {
            h8 af = *(const h8*)(wt[buf] + afo[m]);
            #pragma unroll
            for (int n = 0; n < 2; ++n)
                acce[m][n] = __builtin_amdgcn_mfma_f32_16x16x32_f16(
                    af, bfv[n], acce[m][n], 0, 0, 0);
        }
        if ((T & 3) == 3) {
            int g = T >> 2;
            #pragma unroll
            for (int n = 0; n < 2; ++n)
                #pragma unroll
                for (int m = 0; m < 8; ++m) {
                    accf[m][n] += selr[g][n] * acce[m][n];
                    acce[m][n] = FZ;
                }
        }
        if (hn) write_w(buf ^ 1);
        buf ^= 1;
    }
    // epilogue: + b2 + residual x, fp32 NCHW out
    #pragma unroll
    for (int m = 0; m < 8; ++m) {
        int c0 = wm * 128 + m * 16 + sl * 4;
        f4 bb = *(const f4*)(b2 + c0);
        #pragma unroll
        for (int n = 0; n < 2; ++n) {
            int px = wn * 32 + n * 16 + l15;
            size_t o = (size_t)(b * 256 + c0) * 4096 + p0 + px;
            #pragma unroll
            for (int r = 0; r < 4; ++r)
                out[o + (size_t)r * 4096] = accf[m][n][r] + bb[r] + x[o + (size_t)r * 4096];
        }
    }
}

extern "C" void kernel_launch(void* const* d_in, const int* in_sizes, int n_in,
                              void* d_out, int out_size, void* d_ws, size_t ws_size,
                              hipStream_t stream) {
    const float* x   = (const float*)d_in[0];
    const float* W1  = (const float*)d_in[1];
    const float* b1  = (const float*)d_in[2];
    const float* Wc1 = (const float*)d_in[3];
    const float* bc1 = (const float*)d_in[4];
    const float* W2  = (const float*)d_in[5];
    const float* b2  = (const float*)d_in[6];
    const float* Wc2 = (const float*)d_in[7];
    const float* bc2 = (const float*)d_in[8];
    float* out = (float*)d_out;
    char* ws = (char*)d_ws;
    _Float16* hr  = (_Float16*)(ws);                   // 16,777,216 B
    _Float16* W1r = (_Float16*)(ws + 16777216);        //  4,718,592 B
    _Float16* W2r = (_Float16*)(ws + 21495808);        //    524,288 B
    float* sel1   = (float*)(ws + 22020096);           //  2,097,152 B
    float* sel2   = (float*)(ws + 24117248);           //  2,097,152 B

    hipLaunchKernelGGL(prep_w_k, dim3(10240), dim3(256), 0, stream, W1, W2, W1r, W2r);
    hipLaunchKernelGGL(prep_x_k, dim3(256), dim3(256), 0, stream, x, Wc1, bc1, sel1);
    hipLaunchKernelGGL(conv1_k, dim3(16, 16, 2), dim3(512), 0, stream, x, W1r, sel1, b1, hr);
    hipLaunchKernelGGL(sel2_k, dim3(256), dim3(256), 0, stream, hr, Wc2, bc2, sel2);
    hipLaunchKernelGGL(conv2_k, dim3(1024), dim3(256), 0, stream, hr, W2r, sel2, b2, x, out);
}

// Round 13
// 347.970 us; speedup vs baseline: 4.5790x; 4.5790x over previous
//
#include <hip/hip_runtime.h>
#include <hip/hip_bf16.h>
#include <cstdint>

typedef _Float16 h8 __attribute__((ext_vector_type(8)));
typedef _Float16 h4 __attribute__((ext_vector_type(4)));
typedef float    f4 __attribute__((ext_vector_type(4)));
typedef float    fx16 __attribute__((ext_vector_type(16)));

// Dims: B=16, Cin=256, Ch=128, Br=8, H=W=64, 4096 px/image, 65536 px total.
// ws layout (23 MB):
//   hr   @ 0          16,777,216 B  (f16 [65536 px][128 ch])
//   W1r  @ 16777216    4,718,592 B  (f16 [ci8][tap9][g8][128c][32ch slot-XOR])
//   W2r  @ 21495808      524,288 B  (f16 [g][kc4][256co][32ch])
//   sel1 @ 22020096    2,097,152 B  (f32 [b][g][4096])
//
// LDS involution: 16B slot s at row r lives at slot s ^ ((r>>1)&3)
// (bank-quad of b128 = (r&1)*4 + slot -> 8 consecutive rows cover all 8 quads).
//
// conv1 = R6-exact (measured 264.7 us, 1171 TF): 128c x 256px tile, 512 thr
// (wm2 x wn2, m=2, nf=2, kc=2), 64KB tap staging via GLD16 dbuf, 1 barrier/tap.
// conv2 fuses the coupler-2 softmax (sel2_k removed; hr re-read eliminated).
// prep_w rewritten output-major: coalesced 16B writes, stride-9 gathers.

#define GLD16(src, dst) __builtin_amdgcn_global_load_lds( \
    (const __attribute__((address_space(1))) void*)(src), \
    (__attribute__((address_space(3))) void*)(dst), 16, 0, 0)

// ---------------- prep_w: fp32 -> f16 repack, output-major ----------------
__global__ __launch_bounds__(256) void prep_w_k(const float* __restrict__ W1,
        const float* __restrict__ W2, _Float16* __restrict__ W1r,
        _Float16* __restrict__ W2r) {
    int o8 = blockIdx.x * 256 + threadIdx.x;   // one h8 output group per thread
    if (o8 < 294912) {
        // W1r flat = o8*8 = (cik*9+tap)*32768 + g*4096 + c*32 + sq*8
        int sq = o8 & 3;
        int c  = (o8 >> 2) & 127;
        int g  = (o8 >> 9) & 7;
        int tk = o8 >> 12;                 // cik*9 + tap
        int tap = tk % 9, cik = tk / 9;
        int s = sq ^ ((c >> 1) & 3);
        int ci0 = cik * 32 + s * 8;
        const float* src = W1 + ((size_t)(g * 128 + c) * 256 + ci0) * 9 + tap;
        h8 v;
        #pragma unroll
        for (int e = 0; e < 8; ++e) v[e] = (_Float16)src[e * 9];
        *(h8*)(W1r + (size_t)o8 * 8) = v;
    } else {
        int ow = o8 - 294912;              // W2r h8 groups: 32768
        int sg = ow & 3;
        int co = (ow >> 2) & 255;
        int kc = (ow >> 10) & 3;
        int g  = ow >> 12;
        const float* src = W2 + ((size_t)(g * 256 + co) * 128) + kc * 32 + sg * 8;
        h8 v;
        #pragma unroll
        for (int e = 0; e < 8; ++e) v[e] = (_Float16)src[e];
        *(h8*)(W2r + (size_t)ow * 8) = v;
    }
}

// ---------------- prep_x: sel1 softmax only ----------------
__global__ __launch_bounds__(256) void prep_x_k(const float* __restrict__ x,
        const float* __restrict__ Wc1, const float* __restrict__ bc1,
        float* __restrict__ sel1) {
    __shared__ float wc[2048];            // Wc1 [8][256]
    int t = threadIdx.x;
    for (int i = t; i < 2048; i += 256) wc[i] = Wc1[i];
    __syncthreads();
    int pix = blockIdx.x * 256 + t;       // b*4096 + p
    int b = pix >> 12, p = pix & 4095;
    const float* xp = x + (size_t)b * 1048576 + p;
    float lg[8] = {0.f,0.f,0.f,0.f,0.f,0.f,0.f,0.f};
    for (int c = 0; c < 256; ++c) {
        float v = fmaxf(xp[(size_t)c * 4096], 0.f);
        #pragma unroll
        for (int g = 0; g < 8; ++g) lg[g] += wc[g * 256 + c] * v;
    }
    float m = -1e30f;
    #pragma unroll
    for (int g = 0; g < 8; ++g) { lg[g] += bc1[g]; m = fmaxf(m, lg[g]); }
    float sum = 0.f;
    #pragma unroll
    for (int g = 0; g < 8; ++g) { lg[g] = __expf(lg[g] - m); sum += lg[g]; }
    float inv = 1.f / sum;
    #pragma unroll
    for (int g = 0; g < 8; ++g)
        sel1[(size_t)(b * 8 + g) * 4096 + p] = lg[g] * inv;
}

// ---------------- conv1: R6-exact. switched 3x3, 128c x 256px, 32x32x16 ----
__global__ __launch_bounds__(512, 2) void conv1_k(const float* __restrict__ x,
        const _Float16* __restrict__ W1r, const float* __restrict__ sel1,
        const float* __restrict__ b1, _Float16* __restrict__ hr) {
    __shared__ _Float16 wt[2][32768];     // [buf][g8][128c][32ch slot-XOR]
    __shared__ _Float16 xs[12296];        // [6 rows][64 col][32 ch slot-XOR] + zero @12288
    int t = threadIdx.x;
    int b = blockIdx.y, yt = blockIdx.x;  // yt: group of 4 output rows
    int y0 = yt * 4;
    int w = t >> 6, l = t & 63;
    int wm = w >> 2, wn = w & 3;          // wm: 64-ch half, wn: output row (64px)
    int l31 = l & 31, kq2 = l >> 5;
    if (t < 8) xs[12288 + t] = (_Float16)0.f;   // zero slot

    fx16 acc[2][2];                       // [m][nf]
    #pragma unroll
    for (int m = 0; m < 2; ++m)
        #pragma unroll
        for (int n = 0; n < 2; ++n)
            #pragma unroll
            for (int e = 0; e < 16; ++e) acc[m][n][e] = 0.f;

    // prologue: stage weight group 0 into wt[0]
    {
        const _Float16* srcw = W1r + (size_t)t * 8;
        _Float16* dw = wt[0] + t * 8;
        #pragma unroll
        for (int it = 0; it < 8; ++it)
            GLD16(srcw + it * 4096, dw + it * 4096);
    }

    // lane constants
    int px[2];
    #pragma unroll
    for (int nf = 0; nf < 2; ++nf) px[nf] = wn * 64 + nf * 32 + l31;
    bool e0 = (l31 == 0), e63 = (l31 == 31);
    int afo[2][2];
    #pragma unroll
    for (int m = 0; m < 2; ++m)
        #pragma unroll
        for (int kc = 0; kc < 2; ++kc) {
            int c = wm * 64 + m * 32 + l31;
            afo[m][kc] = c * 32 + (((kc * 2 + kq2) ^ ((c >> 1) & 3)) * 8);
        }
    int ba[2][3][2];
    #pragma unroll
    for (int nf = 0; nf < 2; ++nf)
        #pragma unroll
        for (int kx = 0; kx < 3; ++kx) {
            int rz = px[nf] + kx - 1;
            #pragma unroll
            for (int kc = 0; kc < 2; ++kc)
                ba[nf][kx][kc] = rz * 32 + (((kc * 2 + kq2) ^ ((rz >> 1) & 3)) * 8);
        }
    h8 selv[2];
    #pragma unroll
    for (int nf = 0; nf < 2; ++nf)
        #pragma unroll
        for (int g = 0; g < 8; ++g)
            selv[nf][g] = (_Float16)sel1[(size_t)(b * 8 + g) * 4096 + yt * 256 + px[nf]];

    #pragma unroll 1
    for (int ci = 0; ci < 8; ++ci) {
        __syncthreads();                  // (A) prev ci's xs readers done
        // stage relu(x): 6 in-rows x 64 cols x 32 ch from NCHW fp32, slot-XOR
        if (t < 384) {
            int r = t >> 6, col = t & 63;
            int rc = r * 64 + col;
            int yi = y0 - 1 + r;
            _Float16* dx = xs + rc * 32;
            int rx = (rc >> 1) & 3;
            if (yi >= 0 && yi < 64) {
                const float* xp = x + ((size_t)(b * 256 + ci * 32)) * 4096 + yi * 64 + col;
                float v[32];
                #pragma unroll
                for (int c2 = 0; c2 < 32; ++c2)
                    v[c2] = fmaxf(xp[(size_t)c2 * 4096], 0.f);
                #pragma unroll
                for (int qq = 0; qq < 4; ++qq) {
                    h8 hv;
                    #pragma unroll
                    for (int e = 0; e < 8; ++e) hv[e] = (_Float16)v[qq * 8 + e];
                    *(h8*)(dx + (qq ^ rx) * 8) = hv;   // involution: read undoes it
                }
            } else {
                const h8 HZ = {};
                #pragma unroll
                for (int qq = 0; qq < 4; ++qq)
                    *(h8*)(dx + (qq ^ rx) * 8) = HZ;
            }
        }
        #pragma unroll 1
        for (int ky = 0; ky < 3; ++ky) {
            #pragma unroll
            for (int kx = 0; kx < 3; ++kx) {
                int grp = ci * 9 + ky * 3 + kx;
                __syncthreads();          // publishes wt[grp&1] (vmcnt drain) + xs
                if (grp < 71) {           // async-stage next tap group
                    const _Float16* srcw = W1r + (size_t)(grp + 1) * 32768 + t * 8;
                    _Float16* dw = wt[(grp + 1) & 1] + t * 8;
                    #pragma unroll
                    for (int it = 0; it < 8; ++it)
                        GLD16(srcw + it * 4096, dw + it * 4096);
                }
                // raw B-fragments for this tap (reused across 8 experts)
                h8 bfr[2][2];
                #pragma unroll
                for (int nf = 0; nf < 2; ++nf)
                    #pragma unroll
                    for (int kc = 0; kc < 2; ++kc) {
                        int a = ba[nf][kx][kc] + ky * 2048;
                        if (kx == 0 && nf == 0) a = e0 ? 12288 : a;
                        if (kx == 2 && nf == 1) a = e63 ? 12288 : a;
                        bfr[nf][kc] = *(const h8*)(xs + a);
                    }
                const _Float16* wp = wt[grp & 1];
                #pragma unroll
                for (int g = 0; g < 8; ++g) {
                    h8 a00 = *(const h8*)(wp + g * 4096 + afo[0][0]);
                    h8 a01 = *(const h8*)(wp + g * 4096 + afo[0][1]);
                    h8 a10 = *(const h8*)(wp + g * 4096 + afo[1][0]);
                    h8 a11 = *(const h8*)(wp + g * 4096 + afo[1][1]);
                    #pragma unroll
                    for (int nf = 0; nf < 2; ++nf) {
                        _Float16 sg = selv[nf][g];
                        h8 b0 = bfr[nf][0] * sg;    // sel-scaled B
                        h8 b1v = bfr[nf][1] * sg;
                        acc[0][nf] = __builtin_amdgcn_mfma_f32_32x32x16_f16(
                            a00, b0, acc[0][nf], 0, 0, 0);
                        acc[1][nf] = __builtin_amdgcn_mfma_f32_32x32x16_f16(
                            a10, b0, acc[1][nf], 0, 0, 0);
                        acc[0][nf] = __builtin_amdgcn_mfma_f32_32x32x16_f16(
                            a01, b1v, acc[0][nf], 0, 0, 0);
                        acc[1][nf] = __builtin_amdgcn_mfma_f32_32x32x16_f16(
                            a11, b1v, acc[1][nf], 0, 0, 0);
                    }
                }
            }
        }
    }
    // epilogue: + b1, relu, f16, NHWC hr
    // C/D (32x32): col=lane&31, row=(reg&3)+8*(reg>>2)+4*(lane>>5)
    #pragma unroll
    for (int m = 0; m < 2; ++m)
        #pragma unroll
        for (int nf = 0; nf < 2; ++nf) {
            size_t pg = ((size_t)(b * 4096 + yt * 256 + px[nf])) * 128;
            #pragma unroll
            for (int q = 0; q < 4; ++q) {
                int c0 = wm * 64 + m * 32 + q * 8 + kq2 * 4;
                f4 bb = *(const f4*)(b1 + c0);
                h4 hv;
                #pragma unroll
                for (int r = 0; r < 4; ++r)
                    hv[r] = (_Float16)fmaxf(acc[m][nf][q * 4 + r] + bb[r], 0.f);
                *(h4*)(hr + pg + c0) = hv;
            }
        }
}

// ---------------- conv2: switched 1x1 + fused sel2 softmax + residual ------
__global__ __launch_bounds__(256, 2) void conv2_k(const _Float16* __restrict__ hr,
        const _Float16* __restrict__ W2r, const float* __restrict__ Wc2,
        const float* __restrict__ bc2, const float* __restrict__ b2,
        const float* __restrict__ x, float* __restrict__ out) {
    __shared__ _Float16 hs[64 * 128];        // [64 px][128 ch] swizzled (16KB)
    __shared__ _Float16 wt[2][256 * 32];     // dbuf [256 co][32 ch] swizzled (32KB)
    __shared__ float wc[1024];               // Wc2 [8][128] (4KB)
    __shared__ float red[2048];              // [64 px][8 g][4 strip] (8KB)
    __shared__ float selw[512];              // [64 px][8 g] (2KB)
    int t = threadIdx.x;
    int bid = blockIdx.x;
    int b = bid >> 6, p0 = (bid & 63) * 64;
    int l = t & 63, w = t >> 6;
    int wm = w >> 1, wn = w & 1;
    int l15 = l & 15, sl = l >> 4;
    int swl = (l15 & 7) << 3;
    const f4 FZ = {0.f, 0.f, 0.f, 0.f};
    f4 acce[8][2], accf[8][2];
    #pragma unroll
    for (int m = 0; m < 8; ++m)
        #pragma unroll
        for (int n = 0; n < 2; ++n) { acce[m][n] = FZ; accf[m][n] = FZ; }
    for (int i = t; i < 1024; i += 256) wc[i] = Wc2[i];
    {   // stage h tile (swizzled)
        int px = t >> 2, qq = t & 3;
        const _Float16* src = hr + (size_t)(b * 4096 + p0 + px) * 128 + qq * 32;
        #pragma unroll
        for (int u = 0; u < 4; ++u)
            *(h8*)(hs + ((px * 128 + qq * 32 + u * 8) ^ ((px & 7) << 3)))
                = *(const h8*)(src + u * 8);
    }
    h8 wr[4];
    auto load_w = [&](int T) {
        const _Float16* srcw = W2r + (size_t)T * 8192;
        #pragma unroll
        for (int it = 0; it < 4; ++it)
            wr[it] = *(const h8*)(srcw + (size_t)(it * 256 + t) * 8);
    };
    auto write_w = [&](int bf) {
        #pragma unroll
        for (int it = 0; it < 4; ++it) {
            int cc = it * 256 + t;
            int c = cc >> 2, q = cc & 3;
            *(h8*)(wt[bf] + ((c * 32 + q * 8) ^ ((c & 7) << 3))) = wr[it];
        }
    };
    load_w(0);
    __syncthreads();                      // publish hs + wc
    {   // fused sel2: partial logits (4 threads/px x 32 ch)
        int px = t >> 2, qq = t & 3;
        float lg[8] = {0.f,0.f,0.f,0.f,0.f,0.f,0.f,0.f};
        #pragma unroll
        for (int u = 0; u < 4; ++u) {
            h8 v = *(const h8*)(hs + ((px * 128 + qq * 32 + u * 8) ^ ((px & 7) << 3)));
            #pragma unroll
            for (int e = 0; e < 8; ++e) {
                float f = (float)v[e];
                int c = qq * 32 + u * 8 + e;
                #pragma unroll
                for (int g = 0; g < 8; ++g) lg[g] += wc[g * 128 + c] * f;
            }
        }
        #pragma unroll
        for (int g = 0; g < 8; ++g) red[(px * 8 + g) * 4 + qq] = lg[g];
    }
    __syncthreads();
    if (t < 64) {                         // softmax per pixel
        float lg[8]; float m = -1e30f;
        #pragma unroll
        for (int g = 0; g < 8; ++g) {
            lg[g] = red[(t*8+g)*4+0] + red[(t*8+g)*4+1]
                  + red[(t*8+g)*4+2] + red[(t*8+g)*4+3] + bc2[g];
            m = fmaxf(m, lg[g]);
        }
        float sum = 0.f;
        #pragma unroll
        for (int g = 0; g < 8; ++g) { lg[g] = __expf(lg[g] - m); sum += lg[g]; }
        float inv = 1.f / sum;
        #pragma unroll
        for (int g = 0; g < 8; ++g) selw[t * 8 + g] = lg[g] * inv;
    }
    write_w(0);                           // wt[0] LDS writes (no reader yet)
    __syncthreads();                      // publish selw + wt[0]
    float selr[8][2];
    #pragma unroll
    for (int g = 0; g < 8; ++g)
        #pragma unroll
        for (int n = 0; n < 2; ++n)
            selr[g][n] = selw[(wn * 32 + n * 16 + l15) * 8 + g];
    int afo[8];
    #pragma unroll
    for (int m = 0; m < 8; ++m) {
        int c = wm * 128 + m * 16 + l15;
        afo[m] = ((c * 32 + sl * 8) ^ swl);
    }
    int buf = 0;
    #pragma unroll 1
    for (int T = 0; T < 32; ++T) {          // T = g*4 + kchunk
        bool hn = (T < 31);
        if (hn) load_w(T + 1);
        __syncthreads();   // publishes wt[buf]
        int kc = (T & 3) * 32;
        h8 bfv[2];
        #pragma unroll
        for (int n = 0; n < 2; ++n) {
            int px = wn * 32 + n * 16 + l15;
            bfv[n] = *(const h8*)(hs + ((px * 128 + kc + sl * 8) ^ ((px & 7) << 3)));
        }
        #pragma unroll
        for (int m = 0; m < 8; ++m) {
            h8 af = *(const h8*)(wt[buf] + afo[m]);
            #pragma unroll
            for (int n = 0; n < 2; ++n)
                acce[m][n] = __builtin_amdgcn_mfma_f32_16x16x32_f16(
                    af, bfv[n], acce[m][n], 0, 0, 0);
        }
        if ((T & 3) == 3) {
            int g = T >> 2;
            #pragma unroll
            for (int n = 0; n < 2; ++n)
                #pragma unroll
                for (int m = 0; m < 8; ++m) {
                    accf[m][n] += selr[g][n] * acce[m][n];
                    acce[m][n] = FZ;
                }
        }
        if (hn) write_w(buf ^ 1);
        buf ^= 1;
    }
    // epilogue: + b2 + residual x, fp32 NCHW out
    #pragma unroll
    for (int m = 0; m < 8; ++m) {
        int c0 = wm * 128 + m * 16 + sl * 4;
        f4 bb = *(const f4*)(b2 + c0);
        #pragma unroll
        for (int n = 0; n < 2; ++n) {
            int px = wn * 32 + n * 16 + l15;
            size_t o = (size_t)(b * 256 + c0) * 4096 + p0 + px;
            #pragma unroll
            for (int r = 0; r < 4; ++r)
                out[o + (size_t)r * 4096] = accf[m][n][r] + bb[r] + x[o + (size_t)r * 4096];
        }
    }
}

extern "C" void kernel_launch(void* const* d_in, const int* in_sizes, int n_in,
                              void* d_out, int out_size, void* d_ws, size_t ws_size,
                              hipStream_t stream) {
    const float* x   = (const float*)d_in[0];
    const float* W1  = (const float*)d_in[1];
    const float* b1  = (const float*)d_in[2];
    const float* Wc1 = (const float*)d_in[3];
    const float* bc1 = (const float*)d_in[4];
    const float* W2  = (const float*)d_in[5];
    const float* b2  = (const float*)d_in[6];
    const float* Wc2 = (const float*)d_in[7];
    const float* bc2 = (const float*)d_in[8];
    float* out = (float*)d_out;
    char* ws = (char*)d_ws;
    _Float16* hr  = (_Float16*)(ws);                   // 16,777,216 B
    _Float16* W1r = (_Float16*)(ws + 16777216);        //  4,718,592 B
    _Float16* W2r = (_Float16*)(ws + 21495808);        //    524,288 B
    float* sel1   = (float*)(ws + 22020096);           //  2,097,152 B

    hipLaunchKernelGGL(prep_w_k, dim3(1280), dim3(256), 0, stream, W1, W2, W1r, W2r);
    hipLaunchKernelGGL(prep_x_k, dim3(256), dim3(256), 0, stream, x, Wc1, bc1, sel1);
    hipLaunchKernelGGL(conv1_k, dim3(16, 16), dim3(512), 0, stream, x, W1r, sel1, b1, hr);
    hipLaunchKernelGGL(conv2_k, dim3(1024), dim3(256), 0, stream, hr, W2r, Wc2, bc2, b2, x, out);
}